// Round 2
// baseline (208.497 us; speedup 1.0000x reference)
//
#include <hip/hip_runtime.h>
#include <stdint.h>

typedef __bf16 bf16;
typedef __bf16 bf16x2 __attribute__((ext_vector_type(2)));
typedef __bf16 bf16x4 __attribute__((ext_vector_type(4)));
typedef __bf16 bf16x8 __attribute__((ext_vector_type(8)));
typedef float  f32x4  __attribute__((ext_vector_type(4)));

#if __has_builtin(__builtin_amdgcn_exp2f)
#define EXP2F(x) __builtin_amdgcn_exp2f(x)
#else
#define EXP2F(x) exp2f(x)
#endif

#define GLD_LDS16(g, l)                                                                    \
  __builtin_amdgcn_global_load_lds((const __attribute__((address_space(1))) uint32_t*)(g), \
                                   (__attribute__((address_space(3))) uint32_t*)(l), 16, 0, 0)

constexpr int Bn = 8192, Sn = 256, Rn = 8192;
constexpr int BM = 64, BK = 32, KP = 4;
constexpr int KLEN = Rn / KP;  // 2048 -> 64 chunks of 32

// ---------- fused prep: params + perb + inc->bf16 + zero(out) ----------
__global__ __launch_bounds__(256) void prep_all(
    const float* __restrict__ inc, bf16* __restrict__ incb, float* __restrict__ out,
    const float* __restrict__ alpha, const float* __restrict__ beta,
    const float* __restrict__ gam, const int* __restrict__ rm, const int* __restrict__ rtype,
    float4* __restrict__ params, const float* __restrict__ temp,
    const float* __restrict__ cr, const float* __restrict__ fuv, float4* __restrict__ perb) {
  const int g = blockIdx.x, tid = threadIdx.x;
  if (g < 1024) {
    // incidence fp32 -> bf16 (2M elems)
    size_t i = ((size_t)g * 256 + tid) * 8;
    float4 v0 = *(const float4*)(inc + i);
    float4 v1 = *(const float4*)(inc + i + 4);
    bf16x8 o;
    o[0] = (bf16)v0.x; o[1] = (bf16)v0.y; o[2] = (bf16)v0.z; o[3] = (bf16)v0.w;
    o[4] = (bf16)v1.x; o[5] = (bf16)v1.y; o[6] = (bf16)v1.z; o[7] = (bf16)v1.w;
    *(bf16x8*)(incb + i) = o;
    if (g < 32) {
      int r = g * 256 + tid;
      float a = alpha[r], be = beta[r], gm = gam[r];
      int ty = rtype[r];
      int i0 = rm[2 * r], i1 = rm[2 * r + 1];
      float A = a, P = 0.0f, Q = 0.0f;
      if (ty == 0) { P = be; Q = gm; }
      else if (ty == 2) { A = a * expf(-gm); }
      uint32_t bits = (uint32_t)i0 | ((uint32_t)i1 << 10) | ((uint32_t)ty << 20);
      params[r] = make_float4(A, P, Q, __uint_as_float(bits));
    }
  } else {
    // zero the 8 MB output (2M floats)
    int gg = g - 1024;
    size_t base = (size_t)gg * 2048 + (size_t)tid * 8;
    *(float4*)(out + base) = make_float4(0.f, 0.f, 0.f, 0.f);
    *(float4*)(out + base + 4) = make_float4(0.f, 0.f, 0.f, 0.f);
    if (gg < 32) {
      int b = gg * 256 + tid;
      float T = temp[b];
      perb[b] = make_float4(log2f(T * (1.0f / 300.0f)), 1.4426950408889634f / T, cr[b], fuv[b]);
    }
  }
}

// ---------- fused flux + GEMM ----------
__global__ __launch_bounds__(256, 3) void flux_gemm(
    const float* __restrict__ abund, const float4* __restrict__ perb,
    const float4* __restrict__ params, const bf16* __restrict__ incb,
    float* __restrict__ out) {
  __shared__ bf16 ab_lds[257 * 64];   // [s][b], row 128B = full 32 banks
  __shared__ bf16 inc_lds[256 * BK];  // [n][k], rows 64B (B-fragment order)
  __shared__ bf16 flux_lds[64 * 32];  // [m][k], 64B rows, 8-elem blocks XOR-swizzled by (m>>2)&3

  const int tid  = threadIdx.x;
  const int lane = tid & 63;
  const int w    = tid >> 6;
  const int kp   = blockIdx.x & (KP - 1);
  const int m0g  = (blockIdx.x >> 2) * BM;
  const int kstart = kp * KLEN;
  const int r16 = lane & 15, q = lane >> 4;

  // flux ownership: 4 consecutive m x 2 consecutive k per thread
  const int fm0 = (tid & 15) * 4;   // local m base (4-aligned)
  const int fkk = (tid >> 4) * 2;   // local k base (even)

  // ---- stage abundances tile transposed [s][b] (once per block) ----
  {
    int bsub = tid >> 2;
    int scol = (tid & 3) * 64;
    const float* rowp = abund + (size_t)(m0g + bsub) * Sn + scol;
#pragma unroll
    for (int j = 0; j < 16; ++j) {
      float4 v = *(const float4*)(rowp + j * 4);
      int s = scol + j * 4;
      ab_lds[(s + 0) * 64 + bsub] = (bf16)v.x;
      ab_lds[(s + 1) * 64 + bsub] = (bf16)v.y;
      ab_lds[(s + 2) * 64 + bsub] = (bf16)v.z;
      ab_lds[(s + 3) * 64 + bsub] = (bf16)v.w;
    }
    if (tid < 64) ab_lds[256 * 64 + tid] = (bf16)1.0f;  // ones row (index S)
  }

  // per-b constants for this thread's 4 m rows
  float l2t[4], itv[4], crv[4], fuvv[4];
#pragma unroll
  for (int i = 0; i < 4; ++i) {
    float4 pb = perb[m0g + fm0 + i];
    l2t[i] = pb.x; itv[i] = pb.y; crv[i] = pb.z; fuvv[i] = pb.w;
  }

  f32x4 acc[4][4];
#pragma unroll
  for (int i = 0; i < 4; ++i)
#pragma unroll
    for (int j = 0; j < 4; ++j) acc[i][j] = (f32x4)0.0f;

  for (int c = 0; c < KLEN / BK; ++c) {
    const int kb = kstart + c * BK;
    __syncthreads();  // frag reads of prev chunk done (and ab staging on c==0)

    // async stage incidence tile [256 x 32] bf16
#pragma unroll
    for (int i = 0; i < 4; ++i) {
      int rrow = w * 64 + i * 16 + (lane >> 2);
      const bf16* gp = incb + (size_t)rrow * Rn + kb + (lane & 3) * 8;
      bf16* lp = inc_lds + (w * 64 + i * 16) * BK;  // wave-uniform base
      GLD_LDS16(gp, lp);
    }

    // flux: 2 k x 4 m per thread, b64 gathers
    bf16 fl[2][4];
#pragma unroll
    for (int t = 0; t < 2; ++t) {
      float4 pr = params[kb + fkk + t];
      uint32_t bits = __float_as_uint(pr.w);
      int i0 = bits & 1023;
      int i1 = (bits >> 10) & 1023;
      int ms = (int)(bits >> 20);
      bf16x4 a0 = *(const bf16x4*)(ab_lds + i0 * 64 + fm0);
      bf16x4 a1 = *(const bf16x4*)(ab_lds + i1 * 64 + fm0);
#pragma unroll
      for (int i = 0; i < 4; ++i) {
        float e = pr.y * l2t[i] - pr.z * itv[i];
        float v = EXP2F(e);
        float mult = (ms == 1) ? crv[i] : ((ms == 2) ? fuvv[i] : 1.0f);
        float f = pr.x * v * mult * (float)a0[i] * (float)a1[i];
        fl[t][i] = (bf16)f;
      }
    }
    // swizzled b32 writes: block = (k>>3) ^ ((m>>2)&3)
#pragma unroll
    for (int i = 0; i < 4; ++i) {
      int m = fm0 + i;
      int sw = (fkk >> 3) ^ ((m >> 2) & 3);
      bf16x2 pairv; pairv[0] = fl[0][i]; pairv[1] = fl[1][i];
      *(bf16x2*)(flux_lds + m * 32 + sw * 8 + (fkk & 7)) = pairv;
    }

    __syncthreads();  // drains vmcnt (global_load_lds) + lgkm (ds writes)

    bf16x8 af[4], bfr[4];
#pragma unroll
    for (int mt = 0; mt < 4; ++mt) {
      int m = mt * 16 + r16;
      int sw = q ^ ((m >> 2) & 3);
      af[mt] = *(const bf16x8*)(flux_lds + m * 32 + sw * 8);
    }
#pragma unroll
    for (int nt = 0; nt < 4; ++nt)
      bfr[nt] = *(const bf16x8*)(inc_lds + (w * 64 + nt * 16 + r16) * BK + q * 8);
#pragma unroll
    for (int mt = 0; mt < 4; ++mt)
#pragma unroll
      for (int nt = 0; nt < 4; ++nt)
        acc[mt][nt] = __builtin_amdgcn_mfma_f32_16x16x32_bf16(af[mt], bfr[nt], acc[mt][nt], 0, 0, 0);
  }

  // epilogue: split-K partial -> atomic accumulate
#pragma unroll
  for (int mt = 0; mt < 4; ++mt)
#pragma unroll
    for (int nt = 0; nt < 4; ++nt) {
      int col = w * 64 + nt * 16 + r16;
      int row = m0g + mt * 16 + q * 4;
#pragma unroll
      for (int rg = 0; rg < 4; ++rg)
        atomicAdd(out + (size_t)(row + rg) * Sn + col, acc[mt][nt][rg]);
    }
}

// ---------- launch ----------
extern "C" void kernel_launch(void* const* d_in, const int* in_sizes, int n_in,
                              void* d_out, int out_size, void* d_ws, size_t ws_size,
                              hipStream_t stream) {
  const float* abund = (const float*)d_in[1];
  const float* temp  = (const float*)d_in[2];
  const float* cr    = (const float*)d_in[3];
  const float* fuv   = (const float*)d_in[4];
  const float* inc   = (const float*)d_in[5];
  const float* alpha = (const float*)d_in[6];
  const float* beta  = (const float*)d_in[7];
  const float* gam   = (const float*)d_in[8];
  const int*   rm    = (const int*)d_in[9];
  const int*   rty   = (const int*)d_in[10];
  float* out = (float*)d_out;

  float4* params = (float4*)d_ws;
  float4* perb   = params + Rn;
  bf16*   incb   = (bf16*)(perb + Bn);

  prep_all<<<2048, 256, 0, stream>>>(inc, incb, out, alpha, beta, gam, rm, rty,
                                     params, temp, cr, fuv, perb);
  flux_gemm<<<(Bn / BM) * KP, 256, 0, stream>>>(abund, perb, params, incb, out);
}

// Round 3
// 206.311 us; speedup vs baseline: 1.0106x; 1.0106x over previous
//
#include <hip/hip_runtime.h>
#include <stdint.h>

typedef __bf16 bf16;
typedef __bf16 bf16x8 __attribute__((ext_vector_type(8)));
typedef float  f32x4  __attribute__((ext_vector_type(4)));

#if __has_builtin(__builtin_amdgcn_exp2f)
#define EXP2F(x) __builtin_amdgcn_exp2f(x)
#else
#define EXP2F(x) exp2f(x)
#endif

#define GLD_LDS16(g, l)                                                                    \
  __builtin_amdgcn_global_load_lds((const __attribute__((address_space(1))) uint32_t*)(g), \
                                   (__attribute__((address_space(3))) uint32_t*)(l), 16, 0, 0)

constexpr int Bn = 8192, Sn = 256, Rn = 8192;
constexpr int BM = 64, BK = 32, KP = 8;
constexpr int KLEN = Rn / KP;  // 1024 -> 32 chunks of 32

// ---------- fused prep: params + perb + inc->bf16(swizzled) + zero(out) ----------
__global__ __launch_bounds__(256) void prep_all(
    const float* __restrict__ inc, bf16* __restrict__ incb, float* __restrict__ out,
    const float* __restrict__ alpha, const float* __restrict__ beta,
    const float* __restrict__ gam, const int* __restrict__ rm, const int* __restrict__ rtype,
    float4* __restrict__ params, const float* __restrict__ temp,
    const float* __restrict__ cr, const float* __restrict__ fuv, float4* __restrict__ perb) {
  const int g = blockIdx.x, tid = threadIdx.x;
  if (g < 1024) {
    // incidence fp32 -> bf16, 8-elem blocks XOR-swizzled by row so that the
    // contiguous global_load_lds staging lands bank-conflict-free for B-frag reads
    size_t e = ((size_t)g * 256 + tid) * 8;  // 8-aligned within a row (Rn=8192)
    int n = (int)(e >> 13);                  // row (s index)
    int kpos = (int)(e & 8191);
    int sw = (n >> 1) & 3;
    int src = (kpos & ~31) | (((((kpos >> 3) & 3)) ^ sw) << 3);
    const float* sp = inc + ((size_t)n << 13) + src;
    float4 v0 = *(const float4*)(sp);
    float4 v1 = *(const float4*)(sp + 4);
    bf16x8 o;
    o[0] = (bf16)v0.x; o[1] = (bf16)v0.y; o[2] = (bf16)v0.z; o[3] = (bf16)v0.w;
    o[4] = (bf16)v1.x; o[5] = (bf16)v1.y; o[6] = (bf16)v1.z; o[7] = (bf16)v1.w;
    *(bf16x8*)(incb + e) = o;
    if (g < 32) {
      int r = g * 256 + tid;
      float a = alpha[r], be = beta[r], gm = gam[r];
      int ty = rtype[r];
      int i0 = rm[2 * r], i1 = rm[2 * r + 1];
      float A = a, P = 0.0f, Q = 0.0f;
      if (ty == 0) { P = be; Q = gm; }
      else if (ty == 2) { A = a * expf(-gm); }
      uint32_t bits = (uint32_t)i0 | ((uint32_t)i1 << 10) | ((uint32_t)ty << 20);
      params[r] = make_float4(A, P, Q, __uint_as_float(bits));
    }
  } else {
    int gg = g - 1024;
    size_t base = (size_t)gg * 2048 + (size_t)tid * 8;
    *(float4*)(out + base) = make_float4(0.f, 0.f, 0.f, 0.f);
    *(float4*)(out + base + 4) = make_float4(0.f, 0.f, 0.f, 0.f);
    if (gg < 32) {
      int b = gg * 256 + tid;
      float T = temp[b];
      perb[b] = make_float4(log2f(T * (1.0f / 300.0f)), 1.4426950408889634f / T, cr[b], fuv[b]);
    }
  }
}

// ---------- fused flux + GEMM ----------
__global__ __launch_bounds__(256, 3) void flux_gemm(
    const float* __restrict__ abund, const float4* __restrict__ perb,
    const float4* __restrict__ params, const bf16* __restrict__ incb,
    float* __restrict__ out) {
  __shared__ bf16 ab_lds[257 * 64];   // [s][b], rows 128B -> gathers broadcast-free
  __shared__ bf16 inc_lds[256 * BK];  // [n][k], rows 64B, 8-blocks pre-swizzled in incb
  __shared__ bf16 flux_lds[64 * 32];  // [m][k], rows 64B, 8-blocks XOR-swizzled by (m>>1)&3

  const int tid  = threadIdx.x;
  const int lane = tid & 63;
  const int w    = tid >> 6;
  const int kp   = blockIdx.x & (KP - 1);
  const int m0g  = (blockIdx.x >> 3) * BM;
  const int kstart = kp * KLEN;
  const int r16 = lane & 15, q = lane >> 4;
  const int sw16 = (r16 >> 1) & 3;          // frag-read swizzle (same for A and B)
  const int fsw  = w ^ ((lane >> 1) & 3);   // flux-write swizzle (m = lane)

  // ---- stage abundances tile transposed [s][b] (once per block) ----
  {
    int bsub = tid >> 2;
    int scol = (tid & 3) * 64;
    const float* rowp = abund + (size_t)(m0g + bsub) * Sn + scol;
#pragma unroll
    for (int j = 0; j < 16; ++j) {
      float4 v = *(const float4*)(rowp + j * 4);
      int s = scol + j * 4;
      ab_lds[(s + 0) * 64 + bsub] = (bf16)v.x;
      ab_lds[(s + 1) * 64 + bsub] = (bf16)v.y;
      ab_lds[(s + 2) * 64 + bsub] = (bf16)v.z;
      ab_lds[(s + 3) * 64 + bsub] = (bf16)v.w;
    }
    if (tid < 64) ab_lds[256 * 64 + tid] = (bf16)1.0f;  // ones row (species index S)
  }

  // per-b constants (this thread's flux row m = lane)
  float4 pb = perb[m0g + lane];
  const float l2t = pb.x, itv = pb.y, crv = pb.z, fuvv = pb.w;

  f32x4 acc[4][4];
#pragma unroll
  for (int i = 0; i < 4; ++i)
#pragma unroll
    for (int j = 0; j < 4; ++j) acc[i][j] = (f32x4)0.0f;

  for (int c = 0; c < KLEN / BK; ++c) {
    const int kb = kstart + c * BK;
    __syncthreads();  // frag reads of prev chunk complete before LDS overwrite

    // async stage incidence tile [256 n x 32 k] bf16 (rows already swizzled)
#pragma unroll
    for (int i = 0; i < 4; ++i) {
      int rrow = w * 64 + i * 16 + (lane >> 2);
      const bf16* gp = incb + (size_t)rrow * Rn + kb + (lane & 3) * 8;
      bf16* lp = inc_lds + (w * 64 + i * 16) * BK;  // wave-uniform base
      GLD_LDS16(gp, lp);
    }

    // flux: wave w owns k-block w*8..w*8+8, lane owns m = lane.
    // params index wave-uniform -> scalar (SMEM) loads.
    {
      const float4* pw = params + kb + w * 8;
      bf16x8 fv;
#pragma unroll
      for (int j = 0; j < 8; ++j) {
        float4 pr = pw[j];
        uint32_t bits = __float_as_uint(pr.w);
        int i0 = bits & 1023;
        int i1 = (bits >> 10) & 1023;
        int ms = (int)(bits >> 20);
        float a0 = (float)ab_lds[i0 * 64 + lane];
        float a1 = (float)ab_lds[i1 * 64 + lane];
        float e = pr.y * l2t - pr.z * itv;
        float v = EXP2F(e);
        float mult = (ms == 1) ? crv : ((ms == 2) ? fuvv : 1.0f);
        fv[j] = (bf16)(pr.x * v * mult * a0 * a1);
      }
      *(bf16x8*)(flux_lds + lane * 32 + fsw * 8) = fv;  // b128, conflict-free
    }

    __syncthreads();  // drains vmcnt (global_load_lds) + lgkm (ds writes)

    bf16x8 af[4], bfr[4];
#pragma unroll
    for (int mt = 0; mt < 4; ++mt)
      af[mt] = *(const bf16x8*)(flux_lds + (mt * 16 + r16) * 32 + (q ^ sw16) * 8);
#pragma unroll
    for (int nt = 0; nt < 4; ++nt)
      bfr[nt] = *(const bf16x8*)(inc_lds + (w * 64 + nt * 16 + r16) * BK + (q ^ sw16) * 8);
#pragma unroll
    for (int mt = 0; mt < 4; ++mt)
#pragma unroll
      for (int nt = 0; nt < 4; ++nt)
        acc[mt][nt] = __builtin_amdgcn_mfma_f32_16x16x32_bf16(af[mt], bfr[nt], acc[mt][nt], 0, 0, 0);
  }

  // epilogue: split-K partial -> atomic accumulate (verified C/D mapping)
#pragma unroll
  for (int mt = 0; mt < 4; ++mt)
#pragma unroll
    for (int nt = 0; nt < 4; ++nt) {
      int col = w * 64 + nt * 16 + r16;
      int row = m0g + mt * 16 + q * 4;
#pragma unroll
      for (int rg = 0; rg < 4; ++rg)
        atomicAdd(out + (size_t)(row + rg) * Sn + col, acc[mt][nt][rg]);
    }
}

// ---------- launch ----------
extern "C" void kernel_launch(void* const* d_in, const int* in_sizes, int n_in,
                              void* d_out, int out_size, void* d_ws, size_t ws_size,
                              hipStream_t stream) {
  const float* abund = (const float*)d_in[1];
  const float* temp  = (const float*)d_in[2];
  const float* cr    = (const float*)d_in[3];
  const float* fuv   = (const float*)d_in[4];
  const float* inc   = (const float*)d_in[5];
  const float* alpha = (const float*)d_in[6];
  const float* beta  = (const float*)d_in[7];
  const float* gam   = (const float*)d_in[8];
  const int*   rm    = (const int*)d_in[9];
  const int*   rty   = (const int*)d_in[10];
  float* out = (float*)d_out;

  float4* params = (float4*)d_ws;
  float4* perb   = params + Rn;
  bf16*   incb   = (bf16*)(perb + Bn);

  prep_all<<<2048, 256, 0, stream>>>(inc, incb, out, alpha, beta, gam, rm, rty,
                                     params, temp, cr, fuv, perb);
  flux_gemm<<<(Bn / BM) * KP, 256, 0, stream>>>(abund, perb, params, incb, out);
}

// Round 4
// 173.264 us; speedup vs baseline: 1.2033x; 1.1907x over previous
//
#include <hip/hip_runtime.h>
#include <stdint.h>

typedef __bf16 bf16;
typedef __bf16 bf16x8 __attribute__((ext_vector_type(8)));
typedef float  f32x4  __attribute__((ext_vector_type(4)));

#if __has_builtin(__builtin_amdgcn_exp2f)
#define EXP2F(x) __builtin_amdgcn_exp2f(x)
#else
#define EXP2F(x) exp2f(x)
#endif

#define GLD_LDS16(g, l)                                                                    \
  __builtin_amdgcn_global_load_lds((const __attribute__((address_space(1))) uint32_t*)(g), \
                                   (__attribute__((address_space(3))) uint32_t*)(l), 16, 0, 0)

constexpr int Bn = 8192, Sn = 256, Rn = 8192;
constexpr int BM = 64, BK = 32, KP = 4;
constexpr int KLEN = Rn / KP;  // 2048
constexpr int NC = KLEN / BK;  // 64 chunks per block

// ---------- prep: params + perb + inc->bf16 (8-blocks row-swizzled) ----------
__global__ __launch_bounds__(256) void prep_all(
    const float* __restrict__ inc, bf16* __restrict__ incb,
    const float* __restrict__ alpha, const float* __restrict__ beta,
    const float* __restrict__ gam, const int* __restrict__ rm, const int* __restrict__ rtype,
    float4* __restrict__ params, const float* __restrict__ temp,
    const float* __restrict__ cr, const float* __restrict__ fuv, float4* __restrict__ perb) {
  const int g = blockIdx.x, tid = threadIdx.x;
  // incidence fp32 -> bf16 with 8-elem blocks XOR-swizzled by row (bank-conflict-free B-frags)
  size_t e = ((size_t)g * 256 + tid) * 8;
  int n = (int)(e >> 13);
  int kpos = (int)(e & 8191);
  int sw = (n >> 1) & 3;
  int src = (kpos & ~31) | (((((kpos >> 3) & 3)) ^ sw) << 3);
  const float* sp = inc + ((size_t)n << 13) + src;
  float4 v0 = *(const float4*)(sp);
  float4 v1 = *(const float4*)(sp + 4);
  bf16x8 o;
  o[0] = (bf16)v0.x; o[1] = (bf16)v0.y; o[2] = (bf16)v0.z; o[3] = (bf16)v0.w;
  o[4] = (bf16)v1.x; o[5] = (bf16)v1.y; o[6] = (bf16)v1.z; o[7] = (bf16)v1.w;
  *(bf16x8*)(incb + e) = o;
  if (g < 32) {
    int r = g * 256 + tid;
    float a = alpha[r], be = beta[r], gm = gam[r];
    int ty = rtype[r];
    int i0 = rm[2 * r], i1 = rm[2 * r + 1];
    float A = a, P = 0.0f, Q = 0.0f;
    if (ty == 0) { P = be; Q = gm; }
    else if (ty == 2) { A = a * expf(-gm); }
    uint32_t bits = (uint32_t)i0 | ((uint32_t)i1 << 10) | ((uint32_t)ty << 20);
    params[r] = make_float4(A, P, Q, __uint_as_float(bits));
  } else if (g < 64) {
    int b = (g - 32) * 256 + tid;
    float T = temp[b];
    perb[b] = make_float4(log2f(T * (1.0f / 300.0f)), 1.4426950408889634f / T, cr[b], fuv[b]);
  }
}

// ---------- fused flux + GEMM, double-buffered single-barrier K-loop ----------
__global__ __launch_bounds__(256, 2) void flux_gemm(
    const float* __restrict__ abund, const float4* __restrict__ perb,
    const float4* __restrict__ params, const bf16* __restrict__ incb,
    float* __restrict__ partial) {
  __shared__ bf16 ab_lds[257 * 64];        // 32,896 B: [s][b]
  __shared__ bf16 inc_lds[2][256 * BK];    // 32,768 B: [n][k], rows pre-swizzled
  __shared__ bf16 flux_lds[2][64 * BK];    // 8,192 B:  [m][k], blocks XOR-swizzled

  const int tid  = threadIdx.x;
  const int lane = tid & 63;
  const int w    = tid >> 6;
  // XCD-aware: consecutive blockIdx round-robins XCDs; same-XCD blocks share kp
  const int x   = blockIdx.x & 7;
  const int jb  = blockIdx.x >> 3;         // 0..63
  const int kp  = x & 3;
  const int m0g = (jb * 2 + (x >> 2)) * BM;
  const int kstart = kp * KLEN;
  const int r16 = lane & 15, q = lane >> 4;
  const int sw16 = (r16 >> 1) & 3;         // frag-read swizzle
  const int fsw  = w ^ ((lane >> 1) & 3);  // flux-write swizzle

  // issue GLD for chunk 0 early (latency hidden behind ab staging)
#pragma unroll
  for (int i = 0; i < 4; ++i) {
    int rrow = w * 64 + i * 16 + (lane >> 2);
    const bf16* gp = incb + (size_t)rrow * Rn + kstart + (lane & 3) * 8;
    GLD_LDS16(gp, inc_lds[0] + (w * 64 + i * 16) * BK);
  }

  // stage abundances tile transposed [s][b] (once per block)
  {
    int bsub = tid >> 2;
    int scol = (tid & 3) * 64;
    const float* rowp = abund + (size_t)(m0g + bsub) * Sn + scol;
#pragma unroll
    for (int j = 0; j < 16; ++j) {
      float4 v = *(const float4*)(rowp + j * 4);
      int s = scol + j * 4;
      ab_lds[(s + 0) * 64 + bsub] = (bf16)v.x;
      ab_lds[(s + 1) * 64 + bsub] = (bf16)v.y;
      ab_lds[(s + 2) * 64 + bsub] = (bf16)v.z;
      ab_lds[(s + 3) * 64 + bsub] = (bf16)v.w;
    }
    if (tid < 64) ab_lds[256 * 64 + tid] = (bf16)1.0f;  // ones row (species index S)
  }

  float4 pb = perb[m0g + lane];
  const float l2t = pb.x, itv = pb.y, crv = pb.z, fuvv = pb.w;

  __syncthreads();  // ab ready + chunk-0 inc staged

  // flux chunk 0 -> flux_lds[0]
  {
    const float4* pw = params + kstart + w * 8;
    bf16x8 fv;
#pragma unroll
    for (int j = 0; j < 8; ++j) {
      float4 pr = pw[j];
      uint32_t bits = __float_as_uint(pr.w);
      int i0 = bits & 1023, i1 = (bits >> 10) & 1023, ms = (int)(bits >> 20);
      float a0 = (float)ab_lds[i0 * 64 + lane];
      float a1 = (float)ab_lds[i1 * 64 + lane];
      float v = EXP2F(pr.y * l2t - pr.z * itv);
      float mult = (ms == 1) ? crv : ((ms == 2) ? fuvv : 1.0f);
      fv[j] = (bf16)(pr.x * v * mult * a0 * a1);
    }
    *(bf16x8*)(flux_lds[0] + lane * BK + fsw * 8) = fv;
  }

  f32x4 acc[4][4];
#pragma unroll
  for (int i = 0; i < 4; ++i)
#pragma unroll
    for (int j = 0; j < 4; ++j) acc[i][j] = (f32x4)0.0f;

  for (int c = 0; c < NC; ++c) {
    const int cur = c & 1, nxt = cur ^ 1;
    __syncthreads();  // flux_lds[cur] + inc_lds[cur] ready

    bf16x8 af[4], bfr[4];
#pragma unroll
    for (int mt = 0; mt < 4; ++mt)
      af[mt] = *(const bf16x8*)(flux_lds[cur] + (mt * 16 + r16) * BK + (q ^ sw16) * 8);
#pragma unroll
    for (int nt = 0; nt < 4; ++nt)
      bfr[nt] = *(const bf16x8*)(inc_lds[cur] + (w * 64 + nt * 16 + r16) * BK + (q ^ sw16) * 8);

    if (c + 1 < NC) {
      const int kb = kstart + (c + 1) * BK;
      // async stage next inc tile
#pragma unroll
      for (int i = 0; i < 4; ++i) {
        int rrow = w * 64 + i * 16 + (lane >> 2);
        const bf16* gp = incb + (size_t)rrow * Rn + kb + (lane & 3) * 8;
        GLD_LDS16(gp, inc_lds[nxt] + (w * 64 + i * 16) * BK);
      }
      // next flux tile (independent of this chunk's MFMAs -> overlaps)
      const float4* pw = params + kb + w * 8;
      bf16x8 fv;
#pragma unroll
      for (int j = 0; j < 8; ++j) {
        float4 pr = pw[j];
        uint32_t bits = __float_as_uint(pr.w);
        int i0 = bits & 1023, i1 = (bits >> 10) & 1023, ms = (int)(bits >> 20);
        float a0 = (float)ab_lds[i0 * 64 + lane];
        float a1 = (float)ab_lds[i1 * 64 + lane];
        float v = EXP2F(pr.y * l2t - pr.z * itv);
        float mult = (ms == 1) ? crv : ((ms == 2) ? fuvv : 1.0f);
        fv[j] = (bf16)(pr.x * v * mult * a0 * a1);
      }
      *(bf16x8*)(flux_lds[nxt] + lane * BK + fsw * 8) = fv;
    }

#pragma unroll
    for (int mt = 0; mt < 4; ++mt)
#pragma unroll
      for (int nt = 0; nt < 4; ++nt)
        acc[mt][nt] = __builtin_amdgcn_mfma_f32_16x16x32_bf16(af[mt], bfr[nt], acc[mt][nt], 0, 0, 0);
  }

  // epilogue: plain stores of the split-K partial (no atomics, no zero-init needed)
  float* pout = partial + (size_t)kp * Bn * Sn;
#pragma unroll
  for (int mt = 0; mt < 4; ++mt)
#pragma unroll
    for (int nt = 0; nt < 4; ++nt) {
      int col = w * 64 + nt * 16 + r16;
      int row = m0g + mt * 16 + q * 4;
#pragma unroll
      for (int rg = 0; rg < 4; ++rg)
        pout[(size_t)(row + rg) * Sn + col] = acc[mt][nt][rg];
    }
}

// ---------- split-K reduce ----------
__global__ __launch_bounds__(256) void reduce_k(const float* __restrict__ partial,
                                               float* __restrict__ out) {
  size_t i = ((size_t)blockIdx.x * 256 + threadIdx.x) * 4;
  constexpr size_t NS = (size_t)Bn * Sn;
  float4 a = *(const float4*)(partial + i);
  float4 b = *(const float4*)(partial + NS + i);
  float4 c = *(const float4*)(partial + 2 * NS + i);
  float4 d = *(const float4*)(partial + 3 * NS + i);
  float4 r;
  r.x = (a.x + b.x) + (c.x + d.x);
  r.y = (a.y + b.y) + (c.y + d.y);
  r.z = (a.z + b.z) + (c.z + d.z);
  r.w = (a.w + b.w) + (c.w + d.w);
  *(float4*)(out + i) = r;
}

// ---------- launch ----------
extern "C" void kernel_launch(void* const* d_in, const int* in_sizes, int n_in,
                              void* d_out, int out_size, void* d_ws, size_t ws_size,
                              hipStream_t stream) {
  const float* abund = (const float*)d_in[1];
  const float* temp  = (const float*)d_in[2];
  const float* cr    = (const float*)d_in[3];
  const float* fuv   = (const float*)d_in[4];
  const float* inc   = (const float*)d_in[5];
  const float* alpha = (const float*)d_in[6];
  const float* beta  = (const float*)d_in[7];
  const float* gam   = (const float*)d_in[8];
  const int*   rm    = (const int*)d_in[9];
  const int*   rty   = (const int*)d_in[10];
  float* out = (float*)d_out;

  // ws: params f4[8192] | perb f4[8192] | incb bf16[2M] | partial f32[4*2M]  (~36.5 MB)
  float4* params  = (float4*)d_ws;
  float4* perb    = params + Rn;
  bf16*   incb    = (bf16*)(perb + Bn);
  float*  partial = (float*)(incb + (size_t)Sn * Rn);

  prep_all<<<1024, 256, 0, stream>>>(inc, incb, alpha, beta, gam, rm, rty,
                                     params, temp, cr, fuv, perb);
  flux_gemm<<<(Bn / BM) * KP, 256, 0, stream>>>(abund, perb, params, incb, partial);
  reduce_k<<<(Bn * Sn) / 1024, 256, 0, stream>>>(partial, out);
}